// Round 4
// baseline (641.026 us; speedup 1.0000x reference)
//
#include <hip/hip_runtime.h>

typedef __attribute__((ext_vector_type(8))) short short8;
typedef __attribute__((ext_vector_type(4))) float floatx4;

__device__ __forceinline__ float b2f(unsigned int u) { return __uint_as_float(u << 16); }
__device__ __forceinline__ unsigned short f2b(float f) {      // fp32 -> bf16 RNE
    unsigned int u = __float_as_uint(f);
    return (unsigned short)((u + 0x7fffu + ((u >> 16) & 1u)) >> 16);
}
__device__ __forceinline__ unsigned cvtpk(float lo, float hi) {  // 2xf32 -> packed bf16 (RNE)
    unsigned r;
    asm("v_cvt_pk_bf16_f32 %0, %1, %2" : "=v"(r) : "v"(lo), "v"(hi));
    return r;
}

#define EMB 128
#define NN  500000
#define BB  1024
#define NCT 9        // 8 feat col-tiles + 1 gate tile (col 128 = w_mask)
#define GRID 512     // persistent: 2 blocks/CU x 256 CUs

// ---------------------------------------------------------------- dtype detect
__global__ void kdetect(const unsigned short* __restrict__ xr,
                        const int* __restrict__ braw, int* __restrict__ flags, int N)
{
    int lane = threadIdx.x;   // 64 threads
    int good = 0;
#pragma unroll
    for (int j = 0; j < 4; ++j) {
        unsigned short u = xr[lane * 4 + j];
        unsigned e = (u >> 7) & 0xffu;
        if ((e >= 100u && e <= 140u) || u == 0) ++good;
    }
#pragma unroll
    for (int o = 1; o < 64; o <<= 1) good += __shfl_xor(good, o);
    if (lane == 0) {
        flags[0] = (good < 240) ? 1 : 0;
        flags[1] = (braw[N - 1] == 0 && braw[N - 2] != 0) ? 1 : 0;
    }
}

// ---------------------------------------------------------------- init
// wTf fragment-major: wTf[((kk*NCT+ct)*64 + lane)*8 + j]
// = Blogical[n = ct*16 + (lane&15)][k = kk*32 + (lane>>4)*8 + j]
__global__ __launch_bounds__(256)
void kinit(float* __restrict__ denom, float* __restrict__ xg,
           unsigned short* __restrict__ wTf, const void* __restrict__ w_feat_,
           const void* __restrict__ w_mask_, const int* __restrict__ flags)
{
    int i = blockIdx.x * 256 + threadIdx.x;
    if (i < BB) denom[i] = 0.f;
    if (i < BB * EMB) xg[i] = 0.f;
    if (i < 4 * NCT * 512) {
        int blk = i >> 9, rem = i & 511;
        int lane = rem >> 3, j = rem & 7;
        int kk = blk / NCT, ct = blk - kk * NCT;
        int n = ct * 16 + (lane & 15);
        int k = kk * 32 + (lane >> 4) * 8 + j;
        unsigned short v = 0;
        if (n < 128)      v = flags[0] ? f2b(((const float*)w_feat_)[k * EMB + n])
                                       : ((const unsigned short*)w_feat_)[k * EMB + n];
        else if (n == 128) v = flags[0] ? f2b(((const float*)w_mask_)[k])
                                        : ((const unsigned short*)w_mask_)[k];
        wTf[i] = v;
    }
}

// ---------------------------------------------------------------- per-tile compute
// 32x(128 feat + gate) MFMA from register A-fragments, shift-free softmax e,
// segmented scan -> denom atomic, and either register-space accumulation into
// racc (pure-segment tile) or per-lane run-merge atomics (boundary tile).
__device__ __forceinline__ void flush_racc(float (&racc)[8], int& runSeg,
                                           int quad, int l16, float* __restrict__ xg)
{
    if (runSeg >= 0) {
#pragma unroll
        for (int ct = 0; ct < 8; ++ct) {
            float p = racc[ct];
            p += __shfl_xor(p, 16);
            p += __shfl_xor(p, 32);
            if (quad == (ct & 3))
                atomicAdd(&xg[runSeg * EMB + ct * 16 + l16], p);
            racc[ct] = 0.f;
        }
    }
    runSeg = -1;
}

__device__ __forceinline__ void tile_compute(
    const short8 (&afr)[2][4], int t, int N, bool is64,
    const int* __restrict__ braw, const unsigned short* __restrict__ wTf,
    float bm, const float (&bfv)[8],
    float* __restrict__ se, int* __restrict__ sb, int woff,
    int lane, int quad, int l16,
    float* __restrict__ denom, float* __restrict__ xg,
    float (&racc)[8], int& runSeg)
{
    int nb = t << 5;

    // segments for the 32 rows
    if (lane < 32) {
        int n = nb + lane; int s = -1;
        if (n < N) { int v = is64 ? braw[2 * n] : braw[n]; if (v >= 0 && v < BB) s = v; }
        sb[woff + lane] = s;
    }

    floatx4 zero = {0.f, 0.f, 0.f, 0.f};
    floatx4 acc[2][NCT];
#pragma unroll
    for (int rt = 0; rt < 2; ++rt)
#pragma unroll
        for (int ct = 0; ct < NCT; ++ct) acc[rt][ct] = zero;

#pragma unroll
    for (int kk = 0; kk < 4; ++kk) {
#pragma unroll
        for (int ct = 0; ct < NCT; ++ct) {
            short8 bf = *(const short8*)(wTf + ((kk * NCT + ct) << 9) + (lane << 3));
            acc[0][ct] = __builtin_amdgcn_mfma_f32_16x16x32_bf16(afr[0][kk], bf, acc[0][ct], 0, 0, 0);
            acc[1][ct] = __builtin_amdgcn_mfma_f32_16x16x32_bf16(afr[1][kk], bf, acc[1][ct], 0, 0, 0);
        }
    }

    // gate column (col 128 -> l16==0 lanes): C/D row = rt*16 + quad*4 + r
    if (l16 == 0) {
#pragma unroll
        for (int rt = 0; rt < 2; ++rt)
#pragma unroll
            for (int r = 0; r < 4; ++r)
                se[woff + rt * 16 + quad * 4 + r] = acc[rt][8][r];
    }

    // e = exp(gate) (clamp = overflow guard; softmax shift-invariant),
    // 32-elem segmented scan -> one atomicAdd(denom) per run
    if (lane < 32) {
        int sv = sb[woff + lane];
        float g = se[woff + lane] + bm;
        float ev = (sv >= 0) ? __expf(fminf(g, 60.f)) : 0.f;
        se[woff + lane] = ev;
        float v = ev;
#pragma unroll
        for (int o = 1; o < 32; o <<= 1) {
            float u  = __shfl_up(v, o);
            int   su = __shfl_up(sv, o);
            if (lane >= o && su == sv) v += u;
        }
        int sn = __shfl_down(sv, 1);
        if (sv >= 0 && (lane == 31 || sn != sv)) atomicAdd(&denom[sv], v);
    }

    // e for this lane's 8 rows (broadcast LDS reads)
    float er[2][4];
#pragma unroll
    for (int rt = 0; rt < 2; ++rt)
#pragma unroll
        for (int r = 0; r < 4; ++r)
            er[rt][r] = se[woff + rt * 16 + quad * 4 + r];

    int sF = sb[woff], sL = sb[woff + 31];
    if (sF == sL) {
        if (sF >= 0) {
            if (sF != runSeg) { flush_racc(racc, runSeg, quad, l16, xg); runSeg = sF; }
#pragma unroll
            for (int ct = 0; ct < 8; ++ct) {
                float p = 0.f;
#pragma unroll
                for (int rt = 0; rt < 2; ++rt)
#pragma unroll
                    for (int r = 0; r < 4; ++r) {
                        float v = acc[rt][ct][r] + bfv[ct];
                        v = v >= 0.f ? v : 0.01f * v;
                        p += v * er[rt][r];
                    }
                racc[ct] += p;
            }
        }
    } else {
        flush_racc(racc, runSeg, quad, l16, xg);
        int sr[2][4];
#pragma unroll
        for (int rt = 0; rt < 2; ++rt)
#pragma unroll
            for (int r = 0; r < 4; ++r)
                sr[rt][r] = sb[woff + rt * 16 + quad * 4 + r];
#pragma unroll
        for (int ct = 0; ct < 8; ++ct) {
            int col = ct * 16 + l16;
#pragma unroll
            for (int rt = 0; rt < 2; ++rt) {
                float a = 0.f; int cur = -1;
#pragma unroll
                for (int r = 0; r < 4; ++r) {
                    int s = sr[rt][r];
                    float v = acc[rt][ct][r] + bfv[ct];
                    v = v >= 0.f ? v : 0.01f * v;
                    v *= er[rt][r];
                    if (s != cur) {
                        if (cur >= 0) atomicAdd(&xg[cur * EMB + col], a);
                        a = 0.f; cur = s;
                    }
                    if (s >= 0) a += v;
                }
                if (cur >= 0) atomicAdd(&xg[cur * EMB + col], a);
            }
        }
    }
}

// ---------------------------------------------------------------- persistent fused main
// Each wave owns a contiguous chunk of 32-row tiles. Register double-buffer:
// tile t+1's global loads are in flight while tile t is MFMA'd and reduced,
// so the memory pipe never drains. No __syncthreads anywhere.
__global__ __launch_bounds__(256, 2)
void kmain(const void* __restrict__ x_, const int* __restrict__ braw,
           const void* __restrict__ bm_, const void* __restrict__ bf_,
           const unsigned short* __restrict__ wTf, const int* __restrict__ flags,
           float* __restrict__ denom, float* __restrict__ xg, int N)
{
    __shared__ float se[128];   // per-wave 32-slices
    __shared__ int   sb[128];

    int tid = threadIdx.x;
    int wave = tid >> 6, lane = tid & 63;
    int quad = lane >> 4, l16 = lane & 15;
    int woff = wave * 32;
    bool f32  = flags[0] != 0;
    bool is64 = flags[1] != 0;

    int T  = (N + 31) >> 5;
    int NW = gridDim.x * 4;
    int C  = (T + NW - 1) / NW;
    int W  = blockIdx.x * 4 + wave;
    int t0 = W * C;
    int tend = t0 + C; if (tend > T) tend = T;
    if (t0 >= tend) return;

    float bm = f32 ? ((const float*)bm_)[0]
                   : b2f((unsigned int)((const unsigned short*)bm_)[0]);
    float bfv[8];
#pragma unroll
    for (int ct = 0; ct < 8; ++ct)
        bfv[ct] = f32 ? ((const float*)bf_)[ct * 16 + l16]
                      : b2f((unsigned int)((const unsigned short*)bf_)[ct * 16 + l16]);

    float racc[8];
#pragma unroll
    for (int ct = 0; ct < 8; ++ct) racc[ct] = 0.f;
    int runSeg = -1;

    if (f32) {
        const float* xf = (const float*)x_;
        float4 rA[16], rB[16];
        float4 fz = make_float4(0.f, 0.f, 0.f, 0.f);

#define LOADF(dst, tt) do {                                                     \
        int nb_ = (tt) << 5;                                                    \
        _Pragma("unroll")                                                       \
        for (int rt = 0; rt < 2; ++rt) {                                        \
            int n_ = nb_ + rt * 16 + l16;                                       \
            const float* p_ = xf + (size_t)n_ * EMB + quad * 8;                 \
            _Pragma("unroll")                                                   \
            for (int kk = 0; kk < 4; ++kk) {                                    \
                dst[rt * 8 + kk * 2]     = (n_ < N) ? *(const float4*)(p_ + kk * 32)     : fz; \
                dst[rt * 8 + kk * 2 + 1] = (n_ < N) ? *(const float4*)(p_ + kk * 32 + 4) : fz; \
            }                                                                   \
        }                                                                       \
    } while (0)

#define CONVF(afr, src) do {                                                    \
        _Pragma("unroll")                                                       \
        for (int rt = 0; rt < 2; ++rt)                                          \
            _Pragma("unroll")                                                   \
            for (int kk = 0; kk < 4; ++kk) {                                    \
                float4 a_ = src[rt * 8 + kk * 2], b_ = src[rt * 8 + kk * 2 + 1];\
                union { short8 s; unsigned u[4]; } cv_;                         \
                cv_.u[0] = cvtpk(a_.x, a_.y); cv_.u[1] = cvtpk(a_.z, a_.w);     \
                cv_.u[2] = cvtpk(b_.x, b_.y); cv_.u[3] = cvtpk(b_.z, b_.w);     \
                afr[rt][kk] = cv_.s;                                            \
            }                                                                   \
    } while (0)

        int t = t0;
        LOADF(rA, t);
        while (true) {
            {
                short8 afr[2][4];
                CONVF(afr, rA);
                if (t + 1 < tend) LOADF(rB, t + 1);
                tile_compute(afr, t, N, is64, braw, wTf, bm, bfv,
                             se, sb, woff, lane, quad, l16, denom, xg, racc, runSeg);
                ++t; if (t >= tend) break;
            }
            {
                short8 afr[2][4];
                CONVF(afr, rB);
                if (t + 1 < tend) LOADF(rA, t + 1);
                tile_compute(afr, t, N, is64, braw, wTf, bm, bfv,
                             se, sb, woff, lane, quad, l16, denom, xg, racc, runSeg);
                ++t; if (t >= tend) break;
            }
        }
#undef LOADF
#undef CONVF
    } else {
        const unsigned short* xu = (const unsigned short*)x_;
        short8 hA[8], hB[8];
        short8 hz = {0, 0, 0, 0, 0, 0, 0, 0};

#define LOADH(dst, tt) do {                                                     \
        int nb_ = (tt) << 5;                                                    \
        _Pragma("unroll")                                                       \
        for (int rt = 0; rt < 2; ++rt) {                                        \
            int n_ = nb_ + rt * 16 + l16;                                       \
            const unsigned short* p_ = xu + (size_t)n_ * EMB + quad * 8;        \
            _Pragma("unroll")                                                   \
            for (int kk = 0; kk < 4; ++kk)                                      \
                dst[rt * 4 + kk] = (n_ < N) ? *(const short8*)(p_ + kk * 32) : hz; \
        }                                                                       \
    } while (0)

#define COPYH(afr, src) do {                                                    \
        _Pragma("unroll")                                                       \
        for (int rt = 0; rt < 2; ++rt)                                          \
            _Pragma("unroll")                                                   \
            for (int kk = 0; kk < 4; ++kk) afr[rt][kk] = src[rt * 4 + kk];      \
    } while (0)

        int t = t0;
        LOADH(hA, t);
        while (true) {
            {
                short8 afr[2][4];
                COPYH(afr, hA);
                if (t + 1 < tend) LOADH(hB, t + 1);
                tile_compute(afr, t, N, is64, braw, wTf, bm, bfv,
                             se, sb, woff, lane, quad, l16, denom, xg, racc, runSeg);
                ++t; if (t >= tend) break;
            }
            {
                short8 afr[2][4];
                COPYH(afr, hB);
                if (t + 1 < tend) LOADH(hA, t + 1);
                tile_compute(afr, t, N, is64, braw, wTf, bm, bfv,
                             se, sb, woff, lane, quad, l16, denom, xg, racc, runSeg);
                ++t; if (t >= tend) break;
            }
        }
#undef LOADH
#undef COPYH
    }

    flush_racc(racc, runSeg, quad, l16, xg);
}

// ---------------------------------------------------------------- final: normalize + linear + leaky + residual
__global__ __launch_bounds__(128)
void kfinal(const float* __restrict__ xg, const float* __restrict__ denom,
            const void* __restrict__ xg_old_, const void* __restrict__ w_tr_,
            const void* __restrict__ b_tr_, const int* __restrict__ flags,
            void* __restrict__ out_)
{
    __shared__ float cat[2 * EMB];
    int b = blockIdx.x, j = threadIdx.x;
    bool f32 = flags[0] != 0;

    float d = denom[b];
    float xgv = xg[b * EMB + j];
    xgv = (d > 0.f) ? xgv / d : 0.f;
    if (xgv != xgv) xgv = 700.0f;                 // sentinel: NaN escaped kmain
    cat[j] = xgv;
    float old = f32 ? ((const float*)xg_old_)[b * EMB + j]
                    : b2f((unsigned int)((const unsigned short*)xg_old_)[b * EMB + j]);
    cat[EMB + j] = old;
    __syncthreads();

    float acc = f32 ? ((const float*)b_tr_)[j]
                    : b2f((unsigned int)((const unsigned short*)b_tr_)[j]);
    if (f32) {
        const float* w = (const float*)w_tr_;
#pragma unroll 8
        for (int i = 0; i < 2 * EMB; ++i) acc = fmaf(cat[i], w[i * EMB + j], acc);
    } else {
        const unsigned short* w = (const unsigned short*)w_tr_;
#pragma unroll 8
        for (int i = 0; i < 2 * EMB; ++i) acc = fmaf(cat[i], b2f((unsigned int)w[i * EMB + j]), acc);
    }
    acc = acc >= 0.f ? acc : 0.01f * acc;
    acc += old;
    if (acc != acc) acc = 300.0f;                 // sentinel: NaN in kfinal inputs

    if (f32) ((float*)out_)[b * EMB + j] = acc;
    else     ((unsigned short*)out_)[b * EMB + j] = f2b(acc);
}

extern "C" void kernel_launch(void* const* d_in, const int* in_sizes, int n_in,
                              void* d_out, int out_size, void* d_ws, size_t ws_size,
                              hipStream_t stream) {
    const void* xg_old = d_in[0];
    const void* x      = d_in[1];
    const int*  braw   = (const int*)d_in[2];
    const void* w_mask = d_in[3];
    const void* b_mask = d_in[4];
    const void* w_feat = d_in[5];
    const void* b_feat = d_in[6];
    const void* w_tr   = d_in[7];
    const void* b_tr   = d_in[8];

    const int N = NN;

    char* ws = (char*)d_ws;
    size_t off = 0;
    int*   flags = (int*)(ws + off);   off += 64;
    float* denom = (float*)(ws + off); off += (size_t)BB * 4;
    float* xg    = (float*)(ws + off); off += (size_t)BB * EMB * 4;
    unsigned short* wTf = (unsigned short*)(ws + off); off += (size_t)4 * NCT * 512 * 2;

    kdetect<<<1, 64, 0, stream>>>((const unsigned short*)x, braw, flags, N);
    kinit<<<(BB * EMB + 255) / 256, 256, 0, stream>>>(denom, xg, wTf, w_feat, w_mask, flags);
    kmain<<<GRID, 256, 0, stream>>>(x, braw, b_mask, b_feat, wTf, flags, denom, xg, N);
    kfinal<<<BB, 128, 0, stream>>>(xg, denom, xg_old, w_tr, b_tr, flags, d_out);
}

// Round 5
// 406.595 us; speedup vs baseline: 1.5766x; 1.5766x over previous
//
#include <hip/hip_runtime.h>

typedef __attribute__((ext_vector_type(8))) short short8;
typedef __attribute__((ext_vector_type(4))) float floatx4;

__device__ __forceinline__ float b2f(unsigned int u) { return __uint_as_float(u << 16); }
__device__ __forceinline__ unsigned short f2b(float f) {      // fp32 -> bf16 RNE
    unsigned int u = __float_as_uint(f);
    return (unsigned short)((u + 0x7fffu + ((u >> 16) & 1u)) >> 16);
}
__device__ __forceinline__ unsigned cvtpk(float lo, float hi) {  // 2xf32 -> packed bf16 (RNE)
    unsigned r;
    asm("v_cvt_pk_bf16_f32 %0, %1, %2" : "=v"(r) : "v"(lo), "v"(hi));
    return r;
}

#define EMB 128
#define NN  500000
#define BB  1024
#define BM  128      // rows per block (4 waves x 32 rows)
#define NCT 9        // 8 feat col-tiles + 1 gate tile (col 128 = w_mask)

// ---------------------------------------------------------------- init (+ inlined dtype detect)
// Each block detects dtypes locally (cheap, in-register); block 0 publishes
// flags for kmain/kfinal. wTf fragment-major: wTf[((kk*NCT+ct)*64+lane)*8+j]
// = Blogical[n = ct*16 + (lane&15)][k = kk*32 + (lane>>4)*8 + j], where
// Blogical[n][k] = w_feat[k][n] (n<128), w_mask[k] (n==128), 0 else.
__global__ __launch_bounds__(256)
void kinit(float* __restrict__ denom, float* __restrict__ xg,
           unsigned short* __restrict__ wTf, const void* __restrict__ w_feat_,
           const void* __restrict__ w_mask_, const unsigned short* __restrict__ xr,
           const int* __restrict__ braw, int* __restrict__ flags, int N)
{
    __shared__ int sf32;
    int tid = threadIdx.x;
    if (tid < 64) {
        int good = 0;
#pragma unroll
        for (int j = 0; j < 4; ++j) {
            unsigned short u = xr[tid * 4 + j];
            unsigned e = (u >> 7) & 0xffu;
            if ((e >= 100u && e <= 140u) || u == 0) ++good;
        }
#pragma unroll
        for (int o = 1; o < 64; o <<= 1) good += __shfl_xor(good, o);
        if (tid == 0) {
            sf32 = (good < 240) ? 1 : 0;
            if (blockIdx.x == 0) {
                flags[0] = sf32;
                flags[1] = (braw[N - 1] == 0 && braw[N - 2] != 0) ? 1 : 0;
            }
        }
    }
    __syncthreads();
    bool f32 = sf32 != 0;

    int i = blockIdx.x * 256 + tid;
    if (i < BB) denom[i] = 0.f;
    if (i < BB * EMB) xg[i] = 0.f;
    if (i < 4 * NCT * 512) {
        int blk = i >> 9, rem = i & 511;
        int lane = rem >> 3, j = rem & 7;
        int kk = blk / NCT, ct = blk - kk * NCT;
        int n = ct * 16 + (lane & 15);
        int k = kk * 32 + (lane >> 4) * 8 + j;
        unsigned short v = 0;
        if (n < 128)      v = f32 ? f2b(((const float*)w_feat_)[k * EMB + n])
                                  : ((const unsigned short*)w_feat_)[k * EMB + n];
        else if (n == 128) v = f32 ? f2b(((const float*)w_mask_)[k])
                                   : ((const unsigned short*)w_mask_)[k];
        wTf[i] = v;
    }
}

// ---------------------------------------------------------------- fused main (barrier-free, LDS-free A)
// Each wave owns 32 rows. A-fragments load DIRECTLY from global into
// registers as one batch (16 float4 in flight -> one vmcnt window), packed
// to bf16 with v_cvt_pk_bf16_f32. B comes from fragment-major wTf (L1-hot,
// 1KB coalesced per load). 36x MFMA 16x16x32 incl. the gate column, then
// shift-free softmax e=exp(gate), 32-elem segmented scan -> atomicAdd(denom),
// register-space weighted row-reduce -> atomicAdd(xg). No __syncthreads.
__global__ __launch_bounds__(256, 2)
void kmain(const void* __restrict__ x_, const int* __restrict__ braw,
           const void* __restrict__ bm_, const void* __restrict__ bf_,
           const unsigned short* __restrict__ wTf, const int* __restrict__ flags,
           float* __restrict__ denom, float* __restrict__ xg, int N)
{
    __shared__ float se[BM];   // gate, then e, per row (wave-private 32-slices)
    __shared__ int   sb[BM];   // segment per row

    int tid = threadIdx.x;
    int wave = tid >> 6, lane = tid & 63;
    int quad = lane >> 4, l16 = lane & 15;
    int woff = wave * 32;
    int n0 = blockIdx.x * BM + woff;          // first row of this wave's tile
    bool f32  = flags[0] != 0;
    bool is64 = flags[1] != 0;

    // segments for this wave's 32 rows (issued before the x burst)
    if (lane < 32) {
        int n = n0 + lane; int s = -1;
        if (n < N) { int v = is64 ? braw[2 * n] : braw[n]; if (v >= 0 && v < BB) s = v; }
        sb[woff + lane] = s;
    }

    // ---- A-fragments direct to registers (batched loads, one vmcnt window)
    short8 afr[2][4];
    if (f32) {
        const float* xf = (const float*)x_;
        float4 av[16];
        float4 z = make_float4(0.f, 0.f, 0.f, 0.f);
#pragma unroll
        for (int i = 0; i < 16; ++i) av[i] = z;
#pragma unroll
        for (int rt = 0; rt < 2; ++rt) {
            int n = n0 + rt * 16 + l16;
            const float* p = xf + (size_t)n * EMB + quad * 8;
            if (n < N) {
#pragma unroll
                for (int kk = 0; kk < 4; ++kk) {
                    av[rt * 8 + kk * 2]     = *(const float4*)(p + kk * 32);
                    av[rt * 8 + kk * 2 + 1] = *(const float4*)(p + kk * 32 + 4);
                }
            }
        }
#pragma unroll
        for (int rt = 0; rt < 2; ++rt)
#pragma unroll
            for (int kk = 0; kk < 4; ++kk) {
                float4 a = av[rt * 8 + kk * 2], b = av[rt * 8 + kk * 2 + 1];
                union { short8 s; unsigned u[4]; } cv;
                cv.u[0] = cvtpk(a.x, a.y); cv.u[1] = cvtpk(a.z, a.w);
                cv.u[2] = cvtpk(b.x, b.y); cv.u[3] = cvtpk(b.z, b.w);
                afr[rt][kk] = cv.s;
            }
    } else {
        const unsigned short* xu = (const unsigned short*)x_;
        short8 z8 = {0, 0, 0, 0, 0, 0, 0, 0};
#pragma unroll
        for (int rt = 0; rt < 2; ++rt) {
            int n = n0 + rt * 16 + l16;
            const unsigned short* p = xu + (size_t)n * EMB + quad * 8;
#pragma unroll
            for (int kk = 0; kk < 4; ++kk) afr[rt][kk] = z8;
            if (n < N) {
#pragma unroll
                for (int kk = 0; kk < 4; ++kk)
                    afr[rt][kk] = *(const short8*)(p + kk * 32);
            }
        }
    }

    // ---- MFMA: B from fragment-major wTf (L1-hot, 1KB coalesced per load)
    floatx4 zero = {0.f, 0.f, 0.f, 0.f};
    floatx4 acc[2][NCT];
#pragma unroll
    for (int rt = 0; rt < 2; ++rt)
#pragma unroll
        for (int ct = 0; ct < NCT; ++ct) acc[rt][ct] = zero;

#pragma unroll
    for (int kk = 0; kk < 4; ++kk) {
#pragma unroll
        for (int ct = 0; ct < NCT; ++ct) {
            short8 bf = *(const short8*)(wTf + ((kk * NCT + ct) << 9) + (lane << 3));
            acc[0][ct] = __builtin_amdgcn_mfma_f32_16x16x32_bf16(afr[0][kk], bf, acc[0][ct], 0, 0, 0);
            acc[1][ct] = __builtin_amdgcn_mfma_f32_16x16x32_bf16(afr[1][kk], bf, acc[1][ct], 0, 0, 0);
        }
    }

    // gate column (ct==8, col 128 -> l16==0 lanes): C/D row = rt*16 + quad*4 + r
    if (l16 == 0) {
#pragma unroll
        for (int rt = 0; rt < 2; ++rt)
#pragma unroll
            for (int r = 0; r < 4; ++r)
                se[woff + rt * 16 + quad * 4 + r] = acc[rt][8][r];
    }

    float bm = f32 ? ((const float*)bm_)[0]
                   : b2f((unsigned int)((const unsigned short*)bm_)[0]);

    // e = exp(gate) (clamp = overflow guard; softmax is shift-invariant),
    // 32-element segmented scan -> one atomicAdd(denom) per run
    if (lane < 32) {
        int sv = sb[woff + lane];
        float g = se[woff + lane] + bm;
        float ev = (sv >= 0) ? __expf(fminf(g, 60.f)) : 0.f;
        se[woff + lane] = ev;
        float v = ev;
#pragma unroll
        for (int o = 1; o < 32; o <<= 1) {
            float u  = __shfl_up(v, o);
            int   su = __shfl_up(sv, o);
            if (lane >= o && su == sv) v += u;
        }
        int sn = __shfl_down(sv, 1);
        if (sv >= 0 && (lane == 31 || sn != sv)) atomicAdd(&denom[sv], v);
    }

    // per-lane bias for its 8 cols
    float bfv[8];
#pragma unroll
    for (int ct = 0; ct < 8; ++ct)
        bfv[ct] = f32 ? ((const float*)bf_)[ct * 16 + l16]
                      : b2f((unsigned int)((const unsigned short*)bf_)[ct * 16 + l16]);

    // e and segment for this lane's 8 rows (broadcast LDS reads)
    float er[2][4]; int sr[2][4];
#pragma unroll
    for (int rt = 0; rt < 2; ++rt)
#pragma unroll
        for (int r = 0; r < 4; ++r) {
            int lr = rt * 16 + quad * 4 + r;
            er[rt][r] = se[woff + lr];
            sr[rt][r] = sb[woff + lr];
        }

    int sF = sb[woff], sL = sb[woff + 31];
    if (sF == sL) {
        // fast path (~94% of waves): whole tile one segment -> register reduce
        if (sF >= 0) {
#pragma unroll
            for (int ct = 0; ct < 8; ++ct) {
                float p = 0.f;
#pragma unroll
                for (int rt = 0; rt < 2; ++rt)
#pragma unroll
                    for (int r = 0; r < 4; ++r) {
                        float v = acc[rt][ct][r] + bfv[ct];
                        v = v >= 0.f ? v : 0.01f * v;
                        p += v * er[rt][r];
                    }
                p += __shfl_xor(p, 16);   // sum across quads (rows 0..31)
                p += __shfl_xor(p, 32);
                if (quad == (ct & 3))     // spread atomics: 2 per lane
                    atomicAdd(&xg[sF * EMB + ct * 16 + l16], p);
            }
        }
    } else {
        // slow path: per-lane run-merge over its 4-row groups
#pragma unroll
        for (int ct = 0; ct < 8; ++ct) {
            int col = ct * 16 + l16;
#pragma unroll
            for (int rt = 0; rt < 2; ++rt) {
                float a = 0.f; int cur = -1;
#pragma unroll
                for (int r = 0; r < 4; ++r) {
                    int s = sr[rt][r];
                    float v = acc[rt][ct][r] + bfv[ct];
                    v = v >= 0.f ? v : 0.01f * v;
                    v *= er[rt][r];
                    if (s != cur) {
                        if (cur >= 0) atomicAdd(&xg[cur * EMB + col], a);
                        a = 0.f; cur = s;
                    }
                    if (s >= 0) a += v;
                }
                if (cur >= 0) atomicAdd(&xg[cur * EMB + col], a);
            }
        }
    }
}

// ---------------------------------------------------------------- final: normalize + linear + leaky + residual
__global__ __launch_bounds__(128)
void kfinal(const float* __restrict__ xg, const float* __restrict__ denom,
            const void* __restrict__ xg_old_, const void* __restrict__ w_tr_,
            const void* __restrict__ b_tr_, const int* __restrict__ flags,
            void* __restrict__ out_)
{
    __shared__ float cat[2 * EMB];
    int b = blockIdx.x, j = threadIdx.x;
    bool f32 = flags[0] != 0;

    float d = denom[b];
    float xgv = xg[b * EMB + j];
    xgv = (d > 0.f) ? xgv / d : 0.f;
    if (xgv != xgv) xgv = 700.0f;                 // sentinel: NaN escaped kmain
    cat[j] = xgv;
    float old = f32 ? ((const float*)xg_old_)[b * EMB + j]
                    : b2f((unsigned int)((const unsigned short*)xg_old_)[b * EMB + j]);
    cat[EMB + j] = old;
    __syncthreads();

    float acc = f32 ? ((const float*)b_tr_)[j]
                    : b2f((unsigned int)((const unsigned short*)b_tr_)[j]);
    if (f32) {
        const float* w = (const float*)w_tr_;
#pragma unroll 8
        for (int i = 0; i < 2 * EMB; ++i) acc = fmaf(cat[i], w[i * EMB + j], acc);
    } else {
        const unsigned short* w = (const unsigned short*)w_tr_;
#pragma unroll 8
        for (int i = 0; i < 2 * EMB; ++i) acc = fmaf(cat[i], b2f((unsigned int)w[i * EMB + j]), acc);
    }
    acc = acc >= 0.f ? acc : 0.01f * acc;
    acc += old;
    if (acc != acc) acc = 300.0f;                 // sentinel: NaN in kfinal inputs

    if (f32) ((float*)out_)[b * EMB + j] = acc;
    else     ((unsigned short*)out_)[b * EMB + j] = f2b(acc);
}

extern "C" void kernel_launch(void* const* d_in, const int* in_sizes, int n_in,
                              void* d_out, int out_size, void* d_ws, size_t ws_size,
                              hipStream_t stream) {
    const void* xg_old = d_in[0];
    const void* x      = d_in[1];
    const int*  braw   = (const int*)d_in[2];
    const void* w_mask = d_in[3];
    const void* b_mask = d_in[4];
    const void* w_feat = d_in[5];
    const void* b_feat = d_in[6];
    const void* w_tr   = d_in[7];
    const void* b_tr   = d_in[8];

    const int N = NN;

    char* ws = (char*)d_ws;
    size_t off = 0;
    int*   flags = (int*)(ws + off);   off += 64;
    float* denom = (float*)(ws + off); off += (size_t)BB * 4;
    float* xg    = (float*)(ws + off); off += (size_t)BB * EMB * 4;
    unsigned short* wTf = (unsigned short*)(ws + off); off += (size_t)4 * NCT * 512 * 2;

    kinit<<<(BB * EMB + 255) / 256, 256, 0, stream>>>(denom, xg, wTf, w_feat, w_mask,
                                                      (const unsigned short*)x, braw, flags, N);
    kmain<<<(N + BM - 1) / BM, 256, 0, stream>>>(x, braw, b_mask, b_feat, wTf,
                                                 flags, denom, xg, N);
    kfinal<<<BB, 128, 0, stream>>>(xg, denom, xg_old, w_tr, b_tr, flags, d_out);
}

// Round 6
// 395.856 us; speedup vs baseline: 1.6193x; 1.0271x over previous
//
#include <hip/hip_runtime.h>

typedef __attribute__((ext_vector_type(8))) short short8;
typedef __attribute__((ext_vector_type(4))) float floatx4;

__device__ __forceinline__ float b2f(unsigned int u) { return __uint_as_float(u << 16); }
__device__ __forceinline__ unsigned short f2b(float f) {      // fp32 -> bf16 RNE
    unsigned int u = __float_as_uint(f);
    return (unsigned short)((u + 0x7fffu + ((u >> 16) & 1u)) >> 16);
}
__device__ __forceinline__ unsigned cvtpk(float lo, float hi) {  // 2xf32 -> packed bf16 (RNE)
    unsigned r;
    asm("v_cvt_pk_bf16_f32 %0, %1, %2" : "=v"(r) : "v"(lo), "v"(hi));
    return r;
}

#define EMB 128
#define NN  500000
#define BB  1024
#define BM  128      // rows per block (4 waves x 32 rows)
#define NCT 9        // 8 feat col-tiles + 1 gate tile (col 128 = w_mask)

// ---------------------------------------------------------------- init (+ inlined dtype detect)
// Each block detects dtypes locally (cheap, in-register); block 0 publishes
// flags for kmain/kfinal. wTf fragment-major: wTf[((kk*NCT+ct)*64+lane)*8+j]
// = Blogical[n = ct*16 + (lane&15)][k = kk*32 + (lane>>4)*8 + j], where
// Blogical[n][k] = w_feat[k][n] (n<128), w_mask[k] (n==128), 0 else.
__global__ __launch_bounds__(256)
void kinit(float* __restrict__ denom, float* __restrict__ xg,
           unsigned short* __restrict__ wTf, const void* __restrict__ w_feat_,
           const void* __restrict__ w_mask_, const unsigned short* __restrict__ xr,
           const int* __restrict__ braw, int* __restrict__ flags, int N)
{
    __shared__ int sf32;
    int tid = threadIdx.x;
    if (tid < 64) {
        int good = 0;
#pragma unroll
        for (int j = 0; j < 4; ++j) {
            unsigned short u = xr[tid * 4 + j];
            unsigned e = (u >> 7) & 0xffu;
            if ((e >= 100u && e <= 140u) || u == 0) ++good;
        }
#pragma unroll
        for (int o = 1; o < 64; o <<= 1) good += __shfl_xor(good, o);
        if (tid == 0) {
            sf32 = (good < 240) ? 1 : 0;
            if (blockIdx.x == 0) {
                flags[0] = sf32;
                flags[1] = (braw[N - 1] == 0 && braw[N - 2] != 0) ? 1 : 0;
            }
        }
    }
    __syncthreads();
    bool f32 = sf32 != 0;

    int i = blockIdx.x * 256 + tid;
    if (i < BB) denom[i] = 0.f;
    if (i < BB * EMB) xg[i] = 0.f;
    if (i < 4 * NCT * 512) {
        int blk = i >> 9, rem = i & 511;
        int lane = rem >> 3, j = rem & 7;
        int kk = blk / NCT, ct = blk - kk * NCT;
        int n = ct * 16 + (lane & 15);
        int k = kk * 32 + (lane >> 4) * 8 + j;
        unsigned short v = 0;
        if (n < 128)      v = f32 ? f2b(((const float*)w_feat_)[k * EMB + n])
                                  : ((const unsigned short*)w_feat_)[k * EMB + n];
        else if (n == 128) v = f32 ? f2b(((const float*)w_mask_)[k])
                                   : ((const unsigned short*)w_mask_)[k];
        wTf[i] = v;
    }
}

// ---------------------------------------------------------------- fused main
// Each wave owns 32 rows; A-fragments load directly from global into registers
// as one batch, packed to bf16 with v_cvt_pk_bf16_f32. The B operand (wTf,
// 36 KB) is staged ONCE PER BLOCK into LDS (coalesced uint4, conflict-free
// ds_write), so the MFMA loop reads B via conflict-free ds_read_b128 instead
// of 36 L1-thrashing global loads per wave. One __syncthreads total. Then
// shift-free softmax e=exp(gate), 32-elem segmented scan -> atomicAdd(denom),
// register-space weighted row-reduce -> atomicAdd(xg).
__global__ __launch_bounds__(256, 2)
void kmain(const void* __restrict__ x_, const int* __restrict__ braw,
           const void* __restrict__ bm_, const void* __restrict__ bf_,
           const unsigned short* __restrict__ wTf, const int* __restrict__ flags,
           float* __restrict__ denom, float* __restrict__ xg, int N)
{
    __shared__ __align__(16) unsigned short lB[4 * NCT * 512];  // 36864 B
    __shared__ float se[BM];   // gate, then e, per row (wave-private 32-slices)
    __shared__ int   sb[BM];   // segment per row

    int tid = threadIdx.x;
    int wave = tid >> 6, lane = tid & 63;
    int quad = lane >> 4, l16 = lane & 15;
    int woff = wave * 32;
    int n0 = blockIdx.x * BM + woff;          // first row of this wave's tile
    bool f32  = flags[0] != 0;
    bool is64 = flags[1] != 0;

    // segments for this wave's 32 rows (issued before the x burst)
    if (lane < 32) {
        int n = n0 + lane; int s = -1;
        if (n < N) { int v = is64 ? braw[2 * n] : braw[n]; if (v >= 0 && v < BB) s = v; }
        sb[woff + lane] = s;
    }

    // ---- A-fragments direct to registers (batched loads, one vmcnt window)
    short8 afr[2][4];
    float4 av[16];
    if (f32) {
        const float* xf = (const float*)x_;
        float4 z = make_float4(0.f, 0.f, 0.f, 0.f);
#pragma unroll
        for (int i = 0; i < 16; ++i) av[i] = z;
#pragma unroll
        for (int rt = 0; rt < 2; ++rt) {
            int n = n0 + rt * 16 + l16;
            const float* p = xf + (size_t)n * EMB + quad * 8;
            if (n < N) {
#pragma unroll
                for (int kk = 0; kk < 4; ++kk) {
                    av[rt * 8 + kk * 2]     = *(const float4*)(p + kk * 32);
                    av[rt * 8 + kk * 2 + 1] = *(const float4*)(p + kk * 32 + 4);
                }
            }
        }
    } else {
        const unsigned short* xu = (const unsigned short*)x_;
        short8 z8 = {0, 0, 0, 0, 0, 0, 0, 0};
#pragma unroll
        for (int rt = 0; rt < 2; ++rt) {
            int n = n0 + rt * 16 + l16;
            const unsigned short* p = xu + (size_t)n * EMB + quad * 8;
#pragma unroll
            for (int kk = 0; kk < 4; ++kk) afr[rt][kk] = z8;
            if (n < N) {
#pragma unroll
                for (int kk = 0; kk < 4; ++kk)
                    afr[rt][kk] = *(const short8*)(p + kk * 32);
            }
        }
    }

    // ---- stage wTf (36 KB) into LDS: 256 threads x 9 uint4, coalesced global
    // reads, conflict-free contiguous ds_writes. Overlaps the A-load window.
    {
        const uint4* wg = (const uint4*)wTf;
        uint4* wl = (uint4*)lB;
        uint4 wv[9];
#pragma unroll
        for (int i = 0; i < 9; ++i) wv[i] = wg[i * 256 + tid];
#pragma unroll
        for (int i = 0; i < 9; ++i) wl[i * 256 + tid] = wv[i];
    }
    __syncthreads();

    // convert f32 A-batch to bf16 fragments (packed cvt)
    if (f32) {
#pragma unroll
        for (int rt = 0; rt < 2; ++rt)
#pragma unroll
            for (int kk = 0; kk < 4; ++kk) {
                float4 a = av[rt * 8 + kk * 2], b = av[rt * 8 + kk * 2 + 1];
                union { short8 s; unsigned u[4]; } cv;
                cv.u[0] = cvtpk(a.x, a.y); cv.u[1] = cvtpk(a.z, a.w);
                cv.u[2] = cvtpk(b.x, b.y); cv.u[3] = cvtpk(b.z, b.w);
                afr[rt][kk] = cv.s;
            }
    }

    // ---- MFMA: B from LDS (conflict-free ds_read_b128, lgkmcnt-pipelined)
    const short8* lBf = (const short8*)lB;
    floatx4 zero = {0.f, 0.f, 0.f, 0.f};
    floatx4 acc[2][NCT];
#pragma unroll
    for (int rt = 0; rt < 2; ++rt)
#pragma unroll
        for (int ct = 0; ct < NCT; ++ct) acc[rt][ct] = zero;

#pragma unroll
    for (int kk = 0; kk < 4; ++kk) {
#pragma unroll
        for (int ct = 0; ct < NCT; ++ct) {
            short8 bf = lBf[(kk * NCT + ct) * 64 + lane];
            acc[0][ct] = __builtin_amdgcn_mfma_f32_16x16x32_bf16(afr[0][kk], bf, acc[0][ct], 0, 0, 0);
            acc[1][ct] = __builtin_amdgcn_mfma_f32_16x16x32_bf16(afr[1][kk], bf, acc[1][ct], 0, 0, 0);
        }
    }

    // gate column (ct==8, col 128 -> l16==0 lanes): C/D row = rt*16 + quad*4 + r
    if (l16 == 0) {
#pragma unroll
        for (int rt = 0; rt < 2; ++rt)
#pragma unroll
            for (int r = 0; r < 4; ++r)
                se[woff + rt * 16 + quad * 4 + r] = acc[rt][8][r];
    }

    float bm = f32 ? ((const float*)bm_)[0]
                   : b2f((unsigned int)((const unsigned short*)bm_)[0]);

    // e = exp(gate) (clamp = overflow guard; softmax is shift-invariant),
    // 32-element segmented scan -> one atomicAdd(denom) per run
    if (lane < 32) {
        int sv = sb[woff + lane];
        float g = se[woff + lane] + bm;
        float ev = (sv >= 0) ? __expf(fminf(g, 60.f)) : 0.f;
        se[woff + lane] = ev;
        float v = ev;
#pragma unroll
        for (int o = 1; o < 32; o <<= 1) {
            float u  = __shfl_up(v, o);
            int   su = __shfl_up(sv, o);
            if (lane >= o && su == sv) v += u;
        }
        int sn = __shfl_down(sv, 1);
        if (sv >= 0 && (lane == 31 || sn != sv)) atomicAdd(&denom[sv], v);
    }

    // per-lane bias for its 8 cols
    float bfv[8];
#pragma unroll
    for (int ct = 0; ct < 8; ++ct)
        bfv[ct] = f32 ? ((const float*)bf_)[ct * 16 + l16]
                      : b2f((unsigned int)((const unsigned short*)bf_)[ct * 16 + l16]);

    // e and segment for this lane's 8 rows (broadcast LDS reads)
    float er[2][4]; int sr[2][4];
#pragma unroll
    for (int rt = 0; rt < 2; ++rt)
#pragma unroll
        for (int r = 0; r < 4; ++r) {
            int lr = rt * 16 + quad * 4 + r;
            er[rt][r] = se[woff + lr];
            sr[rt][r] = sb[woff + lr];
        }

    int sF = sb[woff], sL = sb[woff + 31];
    if (sF == sL) {
        // fast path (~94% of waves): whole tile one segment -> register reduce
        if (sF >= 0) {
#pragma unroll
            for (int ct = 0; ct < 8; ++ct) {
                float p = 0.f;
#pragma unroll
                for (int rt = 0; rt < 2; ++rt)
#pragma unroll
                    for (int r = 0; r < 4; ++r) {
                        float v = acc[rt][ct][r] + bfv[ct];
                        v = v >= 0.f ? v : 0.01f * v;
                        p += v * er[rt][r];
                    }
                p += __shfl_xor(p, 16);   // sum across quads (rows 0..31)
                p += __shfl_xor(p, 32);
                if (quad == (ct & 3))     // spread atomics: 2 per lane
                    atomicAdd(&xg[sF * EMB + ct * 16 + l16], p);
            }
        }
    } else {
        // slow path: per-lane run-merge over its 4-row groups
#pragma unroll
        for (int ct = 0; ct < 8; ++ct) {
            int col = ct * 16 + l16;
#pragma unroll
            for (int rt = 0; rt < 2; ++rt) {
                float a = 0.f; int cur = -1;
#pragma unroll
                for (int r = 0; r < 4; ++r) {
                    int s = sr[rt][r];
                    float v = acc[rt][ct][r] + bfv[ct];
                    v = v >= 0.f ? v : 0.01f * v;
                    v *= er[rt][r];
                    if (s != cur) {
                        if (cur >= 0) atomicAdd(&xg[cur * EMB + col], a);
                        a = 0.f; cur = s;
                    }
                    if (s >= 0) a += v;
                }
                if (cur >= 0) atomicAdd(&xg[cur * EMB + col], a);
            }
        }
    }
}

// ---------------------------------------------------------------- final: normalize + linear + leaky + residual
__global__ __launch_bounds__(128)
void kfinal(const float* __restrict__ xg, const float* __restrict__ denom,
            const void* __restrict__ xg_old_, const void* __restrict__ w_tr_,
            const void* __restrict__ b_tr_, const int* __restrict__ flags,
            void* __restrict__ out_)
{
    __shared__ float cat[2 * EMB];
    int b = blockIdx.x, j = threadIdx.x;
    bool f32 = flags[0] != 0;

    float d = denom[b];
    float xgv = xg[b * EMB + j];
    xgv = (d > 0.f) ? xgv / d : 0.f;
    if (xgv != xgv) xgv = 700.0f;                 // sentinel: NaN escaped kmain
    cat[j] = xgv;
    float old = f32 ? ((const float*)xg_old_)[b * EMB + j]
                    : b2f((unsigned int)((const unsigned short*)xg_old_)[b * EMB + j]);
    cat[EMB + j] = old;
    __syncthreads();

    float acc = f32 ? ((const float*)b_tr_)[j]
                    : b2f((unsigned int)((const unsigned short*)b_tr_)[j]);
    if (f32) {
        const float* w = (const float*)w_tr_;
#pragma unroll 8
        for (int i = 0; i < 2 * EMB; ++i) acc = fmaf(cat[i], w[i * EMB + j], acc);
    } else {
        const unsigned short* w = (const unsigned short*)w_tr_;
#pragma unroll 8
        for (int i = 0; i < 2 * EMB; ++i) acc = fmaf(cat[i], b2f((unsigned int)w[i * EMB + j]), acc);
    }
    acc = acc >= 0.f ? acc : 0.01f * acc;
    acc += old;
    if (acc != acc) acc = 300.0f;                 // sentinel: NaN in kfinal inputs

    if (f32) ((float*)out_)[b * EMB + j] = acc;
    else     ((unsigned short*)out_)[b * EMB + j] = f2b(acc);
}

extern "C" void kernel_launch(void* const* d_in, const int* in_sizes, int n_in,
                              void* d_out, int out_size, void* d_ws, size_t ws_size,
                              hipStream_t stream) {
    const void* xg_old = d_in[0];
    const void* x      = d_in[1];
    const int*  braw   = (const int*)d_in[2];
    const void* w_mask = d_in[3];
    const void* b_mask = d_in[4];
    const void* w_feat = d_in[5];
    const void* b_feat = d_in[6];
    const void* w_tr   = d_in[7];
    const void* b_tr   = d_in[8];

    const int N = NN;

    char* ws = (char*)d_ws;
    size_t off = 0;
    int*   flags = (int*)(ws + off);   off += 64;
    float* denom = (float*)(ws + off); off += (size_t)BB * 4;
    float* xg    = (float*)(ws + off); off += (size_t)BB * EMB * 4;
    unsigned short* wTf = (unsigned short*)(ws + off); off += (size_t)4 * NCT * 512 * 2;

    kinit<<<(BB * EMB + 255) / 256, 256, 0, stream>>>(denom, xg, wTf, w_feat, w_mask,
                                                      (const unsigned short*)x, braw, flags, N);
    kmain<<<(N + BM - 1) / BM, 256, 0, stream>>>(x, braw, b_mask, b_feat, wTf,
                                                 flags, denom, xg, N);
    kfinal<<<BB, 128, 0, stream>>>(xg, denom, xg_old, w_tr, b_tr, flags, d_out);
}